// Round 9
// baseline (18.336 us; speedup 1.0000x reference)
//
#include <hip/hip_runtime.h>
#include <math.h>

// Problem constants (match reference)
#define NB 32
#define NA 5
#define NC 20
#define NG 19
#define NT 256
#define GG  (NG*NG)                  // 361
#define CELLS (NB*NA*NG*NG)          // 57760
#define CPB 128                      // cells per block (two 64-lane groups)
#define NBLK ((CELLS + CPB - 1)/CPB) // 452
#define NPART (NBLK*2)               // 904 partial records (2 per block)
#define NWAVE 16
#define NTHR (NWAVE*64)              // 1024

#define OBJECT_SCALE   5.0f
#define NOOBJ_SCALE    1.0f
#define CLASS_SCALE    1.0f
#define COORD_SCALE    1.0f

__constant__ float c_aw[5] = {1.3221f, 3.19275f, 5.05587f, 9.47112f, 11.2364f};
__constant__ float c_ah[5] = {1.73145f, 4.00944f, 8.09892f, 4.84053f, 10.0071f};

__device__ __forceinline__ float sigm(float v) { return 1.f / (1.f + expf(-v)); }

// ---- workspace layout (float offsets) ----
#define SUMS_OFF 0      // 3 floats: cls_sum, obj_sum, coord_sum (written by block 0)
#define PART_OFF 16     // NPART*4 floats: (noobj_sum, noobj_cnt, prior_sum, nm_cnt)

// ================= Kernel A =================
// 452 blocks x 1024 threads (16 waves). Each block owns 128 cells:
// grp = wave>>3 picks cells [grp*64, grp*64+63] (cl = lane + grp*64),
// sub = wave&7 picks the target slice j ≡ sub (mod 8):
// dual accumulators j0 = 16i + sub, j1 = j0 + 8, i = 0..15.
// 8x redundant parallel cell decode per 64-cell group (proven R5 pattern),
// halved per-block target staging (proven R8 pattern).
__global__ __launch_bounds__(NTHR)
void k_main(const float* __restrict__ x, const float* __restrict__ tg,
            float* __restrict__ ws_f, float* __restrict__ partials) {
    __shared__ float4 s_corn[NT];     // target box corners (x1,y1,x2,y2)
    __shared__ float  s_s06[NT];      // 0.6 * target area
    __shared__ int    s_mask[CPB];    // 1 if block-local cell is a target cell
    __shared__ float  s_pm[8][CPB];   // per-sub partial max metric
    __shared__ float  s_wred[12];

    const int t = threadIdx.x;
    const int wave = t >> 6, lane = t & 63;
    const int grp = wave >> 3, sub = wave & 7;
    const int cl  = lane + (grp << 6);         // block-local cell 0..127
    const int cellBase = blockIdx.x * CPB;
    const int idx = cellBase + cl;
    const bool valid = idx < CELLS;

    // ---------- issue this thread's 5 cell-channel loads FIRST ----------
    float txv = 0.f, tyv = 0.f, twv = 0.f, thv = 0.f, cfv = 0.f;
    int ca = 0, cgx = 0, cgy = 0;
    if (valid) {
        int gx = idx % NG;
        int r  = idx / NG;
        int gy = r % NG;  r /= NG;
        int a  = r % NA;
        int b  = r / NA;
        ca = a; cgx = gx; cgy = gy;
        int base = ((b*NA + a)*(NC+5))*GG + gy*NG + gx;
        txv = x[base + 0*GG];
        tyv = x[base + 1*GG];
        twv = x[base + 2*GG];
        thv = x[base + 3*GG];
        cfv = x[base + 4*GG];
    }
    if (t < CPB) s_mask[t] = 0;

    // ---------- target staging (threads 0..255, thread t = target t) ----------
    float gxf = 0.f, gyf = 0.f, gw = 0.f, gh = 0.f;
    int si = 0, ci = 0, ai = 0, gxi = 0, gyi = 0, fid = -1;
    if (t < NT) {
        const float2* tg2 = (const float2*)tg;
        float2 p0 = tg2[t*3+0], p1 = tg2[t*3+1], p2 = tg2[t*3+2];
        gxf = p1.x * NG; gyf = p1.y * NG;
        gw  = p2.x * NG; gh  = p2.y * NG;
        si = (int)p0.x; ci = (int)p0.y;
        // division-free argmax: iou_a > iou_b  <=>  inter_a*uni_b > inter_b*uni_a
        float tarea = gw * gh;
        float b_inter = fminf(c_aw[0], gw) * fminf(c_ah[0], gh);
        float b_uni   = c_aw[0]*c_ah[0] + tarea - b_inter;
        #pragma unroll
        for (int a = 1; a < NA; ++a) {
            float inter = fminf(c_aw[a], gw) * fminf(c_ah[a], gh);
            float uni   = c_aw[a]*c_ah[a] + tarea - inter;
            if (inter * b_uni > b_inter * uni) { b_inter = inter; b_uni = uni; ai = a; }
        }
        gxi = (int)gxf; gyi = (int)gyf;
        fid = ((si*NA + ai)*NG + gyi)*NG + gxi;
        float hw = gw*0.5f, hh = gh*0.5f;
        s_corn[t] = make_float4(gxf - hw, gyf - hh, gxf + hw, gyf + hh);
        s_s06[t]  = 0.6f * tarea;
    }
    __syncthreads();   // barrier 1: staging + mask-init complete; cell loads drained

    // ---------- mask scatter (fids distinct -> no racing writes) ----------
    if (t < NT) {
        int rel = fid - cellBase;
        if (rel >= 0 && rel < CPB) s_mask[rel] = 1;
    }
    // ---------- cell decode (register-only, 8x redundant in parallel) ----------
    float bx1 = 1e30f, by1 = 1e30f, bx2 = 1e30f, by2 = 1e30f, cthr = 0.f;
    float sx = 0.f, sy = 0.f;
    if (valid) {
        sx = sigm(txv); sy = sigm(tyv);
        float pw = expf(twv) * c_aw[ca], ph = expf(thv) * c_ah[ca];
        float cx = sx + (float)cgx, cy = sy + (float)cgy;
        bx1 = cx - pw*0.5f; bx2 = cx + pw*0.5f;
        by1 = cy - ph*0.5f; by2 = cy + ph*0.5f;
        cthr = 0.6f * (pw * ph) + 6e-17f;   // 0.6*(area_p + 1e-16)
    }
    __syncthreads();   // barrier 2: mask scatter visible

    // ---------- main loop: 32 targets/wave, dual accumulators, full unroll ----------
    float m0 = -1e30f, m1 = -1e30f;
    #pragma unroll
    for (int i = 0; i < 16; ++i) {
        int j0 = (i << 4) + sub;      // j = 16i + sub
        int j1 = j0 + 8;              // j = 16i + 8 + sub
        float4 ta = s_corn[j0];
        float sa = s_s06[j0];
        float4 tb = s_corn[j1];
        float sb = s_s06[j1];
        float iwa = fmaxf(fminf(bx2, ta.z) - fmaxf(bx1, ta.x), 0.f);
        float iha = fmaxf(fminf(by2, ta.w) - fmaxf(by1, ta.y), 0.f);
        float iwb = fmaxf(fminf(bx2, tb.z) - fmaxf(bx1, tb.x), 0.f);
        float ihb = fmaxf(fminf(by2, tb.w) - fmaxf(by1, tb.y), 0.f);
        // any-IoU>0.6  <=>  max_j(1.6*inter - 0.6*area_t) > 0.6*area_p + 6e-17
        m0 = fmaxf(m0, fmaf(1.6f, iwa * iha, -sa));
        m1 = fmaxf(m1, fmaf(1.6f, iwb * ihb, -sb));
    }
    s_pm[sub][cl] = fmaxf(m0, m1);
    __syncthreads();   // barrier 3: s_pm visible

    // ---------- epilogue: sub==0 waves (one per 64-cell group) ----------
    if (sub == 0) {
        float mm = s_pm[0][cl];
        #pragma unroll
        for (int w = 1; w < 8; ++w) mm = fmaxf(mm, s_pm[w][cl]);
        float v_no = 0.f, v_nc = 0.f, v_pr = 0.f, v_nm = 0.f;
        if (valid && !s_mask[cl]) {
            v_nm = 1.f;
            float e0 = sx - 0.5f, e1 = sy - 0.5f;
            v_pr = e0*e0 + e1*e1 + twv*twv + thv*thv;
            if (!(mm > cthr)) {          // max_iou <= 0.6
                float pc = sigm(cfv);
                v_no = pc * pc;
                v_nc = 1.f;
            }
        }
        #pragma unroll
        for (int off = 32; off > 0; off >>= 1) {
            v_no += __shfl_down(v_no, off);
            v_nc += __shfl_down(v_nc, off);
            v_pr += __shfl_down(v_pr, off);
            v_nm += __shfl_down(v_nm, off);
        }
        if (lane == 0) {
            int p = blockIdx.x*2 + grp;
            partials[p*4 + 0] = v_no;
            partials[p*4 + 1] = v_nc;
            partials[p*4 + 2] = v_pr;
            partials[p*4 + 3] = v_nm;
        }
    }

    // ---------- block 0 only: per-target cls/obj/coord losses ----------
    if (blockIdx.x == 0) {
        float s_cls = 0.f, s_obj = 0.f, s_crd = 0.f;
        if (t < NT) {
            int base = ((si*NA + ai)*(NC+5))*GG + gyi*NG + gxi;
            float txt = x[base + 0*GG];
            float tyt = x[base + 1*GG];
            float twt = x[base + 2*GG];
            float tht = x[base + 3*GG];
            float cft = x[base + 4*GG];
            float tsx = sigm(txt), tsy = sigm(tyt);
            float aw = c_aw[ai], ah = c_ah[ai];
            float pw = expf(twt) * aw, ph = expf(tht) * ah;

            float pcx = tsx + (float)gxi, pcy = tsy + (float)gyi;
            float hw = gw*0.5f, hh = gh*0.5f;
            float iw = fmaxf(0.f, fminf(pcx + pw*0.5f, gxf + hw) - fmaxf(pcx - pw*0.5f, gxf - hw));
            float ih = fmaxf(0.f, fminf(pcy + ph*0.5f, gyf + hh) - fmaxf(pcy - ph*0.5f, gyf - hh));
            float inter = iw * ih;
            float uni = pw*ph + gw*gh - inter;
            float iou = inter / (uni + 1e-16f);

            float pconf = sigm(cft);
            float dobj = pconf - iou;
            s_obj = dobj * dobj;

            for (int cc = 0; cc < NC; ++cc) {
                float pc = sigm(x[base + (5 + cc)*GG]);
                float d = pc - ((cc == ci) ? 1.f : 0.f);
                s_cls += d * d;
            }

            float scl = sqrtf(2.f - gw*gh / (float)(NG*NG));
            float d0 = (tsx - (gxf - (float)gxi)) * scl;
            float d1 = (tsy - (gyf - (float)gyi)) * scl;
            float d2 = (twt - logf(gw / aw)) * scl;
            float d3 = (tht - logf(gh / ah)) * scl;
            s_crd = d0*d0 + d1*d1 + d2*d2 + d3*d3;

            #pragma unroll
            for (int off = 32; off > 0; off >>= 1) {
                s_cls += __shfl_down(s_cls, off);
                s_obj += __shfl_down(s_obj, off);
                s_crd += __shfl_down(s_crd, off);
            }
            if (lane == 0) {
                s_wred[wave*3 + 0] = s_cls;
                s_wred[wave*3 + 1] = s_obj;
                s_wred[wave*3 + 2] = s_crd;
            }
        }
        __syncthreads();
        if (t == 0) {
            ws_f[SUMS_OFF + 0] = s_wred[0] + s_wred[3] + s_wred[6] + s_wred[9];
            ws_f[SUMS_OFF + 1] = s_wred[1] + s_wred[4] + s_wred[7] + s_wred[10];
            ws_f[SUMS_OFF + 2] = s_wred[2] + s_wred[5] + s_wred[8] + s_wred[11];
        }
    }
}

// ================= Kernel B: final deterministic combine (R5/R8-proven shape) =================
__global__ __launch_bounds__(256)
void k_final(const float* __restrict__ ws_f, const float* __restrict__ partials,
             const int* __restrict__ seen, float* __restrict__ out) {
    const float4* p4 = (const float4*)partials;
    int t = threadIdx.x;
    float a0 = 0.f, a1 = 0.f, a2 = 0.f, a3 = 0.f;
    for (int j = t; j < NPART; j += 256) {
        float4 v = p4[j];
        a0 += v.x; a1 += v.y; a2 += v.z; a3 += v.w;
    }
    #pragma unroll
    for (int off = 32; off > 0; off >>= 1) {
        a0 += __shfl_down(a0, off);
        a1 += __shfl_down(a1, off);
        a2 += __shfl_down(a2, off);
        a3 += __shfl_down(a3, off);
    }
    __shared__ float s_w[4][4];
    int wave = t >> 6, lane = t & 63;
    if (lane == 0) {
        s_w[wave][0] = a0; s_w[wave][1] = a1; s_w[wave][2] = a2; s_w[wave][3] = a3;
    }
    __syncthreads();
    if (t == 0) {
        float r0 = s_w[0][0] + s_w[1][0] + s_w[2][0] + s_w[3][0];
        float r1 = s_w[0][1] + s_w[1][1] + s_w[2][1] + s_w[3][1];
        float r2 = s_w[0][2] + s_w[1][2] + s_w[2][2] + s_w[3][2];
        float r3 = s_w[0][3] + s_w[1][3] + s_w[2][3] + s_w[3][3];
        float loss_cls = ws_f[SUMS_OFF + 0] / (float)(NT * NC) * CLASS_SCALE;
        float loss_obj = ws_f[SUMS_OFF + 1] / (float)NT * OBJECT_SCALE;
        float loss_crd = ws_f[SUMS_OFF + 2] / (float)(NT * 4) * COORD_SCALE;
        float loss_no  = r0 / r1 * NOOBJ_SCALE;
        float total = loss_cls + loss_obj + loss_crd + loss_no;
        if (seen[0] < 12800) {
            total += r2 / (r3 * 4.f) * 0.01f;
        }
        out[0] = total;
    }
}

extern "C" void kernel_launch(void* const* d_in, const int* in_sizes, int n_in,
                              void* d_out, int out_size, void* d_ws, size_t ws_size,
                              hipStream_t stream) {
    const float* x    = (const float*)d_in[0];
    const float* tg   = (const float*)d_in[1];
    const int*   seen = (const int*)d_in[2];
    float* out  = (float*)d_out;
    float* ws_f = (float*)d_ws;
    float* partials = ws_f + PART_OFF;

    k_main<<<NBLK, NTHR, 0, stream>>>(x, tg, ws_f, partials);
    k_final<<<1, 256, 0, stream>>>(ws_f, partials, seen, out);
}

// Round 10
// 17.245 us; speedup vs baseline: 1.0632x; 1.0632x over previous
//
#include <hip/hip_runtime.h>
#include <math.h>

// Problem constants (match reference)
#define NB 32
#define NA 5
#define NC 20
#define NG 19
#define NT 256
#define GG  (NG*NG)                  // 361
#define CELLS (NB*NA*NG*NG)          // 57760
#define CPB 128                      // cells per block (two 64-lane groups)
#define NBLK ((CELLS + CPB - 1)/CPB) // 452
#define NPART (NBLK*2)               // 904 partial records (2 per block)
#define NWAVE 8
#define NTHR (NWAVE*64)              // 512

#define OBJECT_SCALE   5.0f
#define NOOBJ_SCALE    1.0f
#define CLASS_SCALE    1.0f
#define COORD_SCALE    1.0f

__constant__ float c_aw[5] = {1.3221f, 3.19275f, 5.05587f, 9.47112f, 11.2364f};
__constant__ float c_ah[5] = {1.73145f, 4.00944f, 8.09892f, 4.84053f, 10.0071f};

__device__ __forceinline__ float sigm(float v) { return 1.f / (1.f + expf(-v)); }

// ---- workspace layout (float offsets) ----
#define SUMS_OFF 0      // 3 floats: cls_sum, obj_sum, coord_sum (written by block 0)
#define PART_OFF 16     // NPART*4 floats: (noobj_sum, noobj_cnt, prior_sum, nm_cnt)

// ================= Kernel A (R8-proven optimum) =================
// 452 blocks x 512 threads (8 waves). Each block owns 128 cells:
// waves 0-3 handle cells 0-63 (cl = lane), waves 4-7 cells 64-127 (cl = lane+64)
// — 4x redundant parallel decode. Wave w scans targets j ≡ (w&3) (mod 4):
// dual accumulators j0 = 8i + (w&3), j1 = j0 + 4, i = 0..31.
__global__ __launch_bounds__(NTHR)
void k_main(const float* __restrict__ x, const float* __restrict__ tg,
            float* __restrict__ ws_f, float* __restrict__ partials) {
    __shared__ float4 s_corn[NT];     // target box corners (x1,y1,x2,y2)
    __shared__ float  s_s06[NT];      // 0.6 * target area
    __shared__ int    s_mask[CPB];    // 1 if block-local cell is a target cell
    __shared__ float  s_pm[4][CPB];   // per-subwave partial max metric
    __shared__ float  s_wred[12];

    const int t = threadIdx.x;
    const int wave = t >> 6, lane = t & 63;
    const int grp = wave >> 2, sub = wave & 3;
    const int cl  = lane + (grp << 6);         // block-local cell 0..127
    const int cellBase = blockIdx.x * CPB;
    const int idx = cellBase + cl;
    const bool valid = idx < CELLS;

    // ---------- issue this thread's 5 cell-channel loads FIRST ----------
    float txv = 0.f, tyv = 0.f, twv = 0.f, thv = 0.f, cfv = 0.f;
    int ca = 0, cgx = 0, cgy = 0;
    if (valid) {
        int gx = idx % NG;
        int r  = idx / NG;
        int gy = r % NG;  r /= NG;
        int a  = r % NA;
        int b  = r / NA;
        ca = a; cgx = gx; cgy = gy;
        int base = ((b*NA + a)*(NC+5))*GG + gy*NG + gx;
        txv = x[base + 0*GG];
        tyv = x[base + 1*GG];
        twv = x[base + 2*GG];
        thv = x[base + 3*GG];
        cfv = x[base + 4*GG];
    }
    if (t < CPB) s_mask[t] = 0;

    // ---------- target staging (threads 0..255, thread t = target t) ----------
    float gxf = 0.f, gyf = 0.f, gw = 0.f, gh = 0.f;
    int si = 0, ci = 0, ai = 0, gxi = 0, gyi = 0, fid = -1;
    if (t < NT) {
        const float2* tg2 = (const float2*)tg;
        float2 p0 = tg2[t*3+0], p1 = tg2[t*3+1], p2 = tg2[t*3+2];
        gxf = p1.x * NG; gyf = p1.y * NG;
        gw  = p2.x * NG; gh  = p2.y * NG;
        si = (int)p0.x; ci = (int)p0.y;
        // division-free argmax: iou_a > iou_b  <=>  inter_a*uni_b > inter_b*uni_a
        float tarea = gw * gh;
        float b_inter = fminf(c_aw[0], gw) * fminf(c_ah[0], gh);
        float b_uni   = c_aw[0]*c_ah[0] + tarea - b_inter;
        #pragma unroll
        for (int a = 1; a < NA; ++a) {
            float inter = fminf(c_aw[a], gw) * fminf(c_ah[a], gh);
            float uni   = c_aw[a]*c_ah[a] + tarea - inter;
            if (inter * b_uni > b_inter * uni) { b_inter = inter; b_uni = uni; ai = a; }
        }
        gxi = (int)gxf; gyi = (int)gyf;
        fid = ((si*NA + ai)*NG + gyi)*NG + gxi;
        float hw = gw*0.5f, hh = gh*0.5f;
        s_corn[t] = make_float4(gxf - hw, gyf - hh, gxf + hw, gyf + hh);
        s_s06[t]  = 0.6f * tarea;
    }
    __syncthreads();   // barrier 1: staging + mask-init complete; cell loads drained

    // ---------- mask scatter (fids distinct -> no racing writes) ----------
    if (t < NT) {
        int rel = fid - cellBase;
        if (rel >= 0 && rel < CPB) s_mask[rel] = 1;
    }
    // ---------- cell decode (register-only, 4x redundant in parallel) ----------
    float bx1 = 1e30f, by1 = 1e30f, bx2 = 1e30f, by2 = 1e30f, cthr = 0.f;
    float sx = 0.f, sy = 0.f;
    if (valid) {
        sx = sigm(txv); sy = sigm(tyv);
        float pw = expf(twv) * c_aw[ca], ph = expf(thv) * c_ah[ca];
        float cx = sx + (float)cgx, cy = sy + (float)cgy;
        bx1 = cx - pw*0.5f; bx2 = cx + pw*0.5f;
        by1 = cy - ph*0.5f; by2 = cy + ph*0.5f;
        cthr = 0.6f * (pw * ph) + 6e-17f;   // 0.6*(area_p + 1e-16)
    }
    __syncthreads();   // barrier 2: mask scatter visible

    // ---------- main loop: 64 targets/wave, dual accumulators, full unroll ----------
    float m0 = -1e30f, m1 = -1e30f;
    #pragma unroll
    for (int i = 0; i < 32; ++i) {
        int j0 = (i << 3) + sub;      // j = 8i + sub
        int j1 = j0 + 4;              // j = 8i + 4 + sub
        float4 ta = s_corn[j0];
        float sa = s_s06[j0];
        float4 tb = s_corn[j1];
        float sb = s_s06[j1];
        float iwa = fmaxf(fminf(bx2, ta.z) - fmaxf(bx1, ta.x), 0.f);
        float iha = fmaxf(fminf(by2, ta.w) - fmaxf(by1, ta.y), 0.f);
        float iwb = fmaxf(fminf(bx2, tb.z) - fmaxf(bx1, tb.x), 0.f);
        float ihb = fmaxf(fminf(by2, tb.w) - fmaxf(by1, tb.y), 0.f);
        // any-IoU>0.6  <=>  max_j(1.6*inter - 0.6*area_t) > 0.6*area_p + 6e-17
        m0 = fmaxf(m0, fmaf(1.6f, iwa * iha, -sa));
        m1 = fmaxf(m1, fmaf(1.6f, iwb * ihb, -sb));
    }
    s_pm[sub][cl] = fmaxf(m0, m1);
    __syncthreads();   // barrier 3: s_pm visible

    // ---------- epilogue: wave 0 (cells 0-63) and wave 4 (cells 64-127) ----------
    if (sub == 0) {
        float mm = fmaxf(fmaxf(s_pm[0][cl], s_pm[1][cl]),
                         fmaxf(s_pm[2][cl], s_pm[3][cl]));
        float v_no = 0.f, v_nc = 0.f, v_pr = 0.f, v_nm = 0.f;
        if (valid && !s_mask[cl]) {
            v_nm = 1.f;
            float e0 = sx - 0.5f, e1 = sy - 0.5f;
            v_pr = e0*e0 + e1*e1 + twv*twv + thv*thv;
            if (!(mm > cthr)) {          // max_iou <= 0.6
                float pc = sigm(cfv);
                v_no = pc * pc;
                v_nc = 1.f;
            }
        }
        #pragma unroll
        for (int off = 32; off > 0; off >>= 1) {
            v_no += __shfl_down(v_no, off);
            v_nc += __shfl_down(v_nc, off);
            v_pr += __shfl_down(v_pr, off);
            v_nm += __shfl_down(v_nm, off);
        }
        if (lane == 0) {
            int p = blockIdx.x*2 + grp;
            partials[p*4 + 0] = v_no;
            partials[p*4 + 1] = v_nc;
            partials[p*4 + 2] = v_pr;
            partials[p*4 + 3] = v_nm;
        }
    }

    // ---------- block 0 only: per-target cls/obj/coord losses ----------
    if (blockIdx.x == 0) {
        float s_cls = 0.f, s_obj = 0.f, s_crd = 0.f;
        if (t < NT) {
            int base = ((si*NA + ai)*(NC+5))*GG + gyi*NG + gxi;
            float txt = x[base + 0*GG];
            float tyt = x[base + 1*GG];
            float twt = x[base + 2*GG];
            float tht = x[base + 3*GG];
            float cft = x[base + 4*GG];
            float tsx = sigm(txt), tsy = sigm(tyt);
            float aw = c_aw[ai], ah = c_ah[ai];
            float pw = expf(twt) * aw, ph = expf(tht) * ah;

            float pcx = tsx + (float)gxi, pcy = tsy + (float)gyi;
            float hw = gw*0.5f, hh = gh*0.5f;
            float iw = fmaxf(0.f, fminf(pcx + pw*0.5f, gxf + hw) - fmaxf(pcx - pw*0.5f, gxf - hw));
            float ih = fmaxf(0.f, fminf(pcy + ph*0.5f, gyf + hh) - fmaxf(pcy - ph*0.5f, gyf - hh));
            float inter = iw * ih;
            float uni = pw*ph + gw*gh - inter;
            float iou = inter / (uni + 1e-16f);

            float pconf = sigm(cft);
            float dobj = pconf - iou;
            s_obj = dobj * dobj;

            for (int cc = 0; cc < NC; ++cc) {
                float pc = sigm(x[base + (5 + cc)*GG]);
                float d = pc - ((cc == ci) ? 1.f : 0.f);
                s_cls += d * d;
            }

            float scl = sqrtf(2.f - gw*gh / (float)(NG*NG));
            float d0 = (tsx - (gxf - (float)gxi)) * scl;
            float d1 = (tsy - (gyf - (float)gyi)) * scl;
            float d2 = (twt - logf(gw / aw)) * scl;
            float d3 = (tht - logf(gh / ah)) * scl;
            s_crd = d0*d0 + d1*d1 + d2*d2 + d3*d3;

            #pragma unroll
            for (int off = 32; off > 0; off >>= 1) {
                s_cls += __shfl_down(s_cls, off);
                s_obj += __shfl_down(s_obj, off);
                s_crd += __shfl_down(s_crd, off);
            }
            if (lane == 0) {
                s_wred[wave*3 + 0] = s_cls;
                s_wred[wave*3 + 1] = s_obj;
                s_wred[wave*3 + 2] = s_crd;
            }
        }
        __syncthreads();
        if (t == 0) {
            ws_f[SUMS_OFF + 0] = s_wred[0] + s_wred[3] + s_wred[6] + s_wred[9];
            ws_f[SUMS_OFF + 1] = s_wred[1] + s_wred[4] + s_wred[7] + s_wred[10];
            ws_f[SUMS_OFF + 2] = s_wred[2] + s_wred[5] + s_wred[8] + s_wred[11];
        }
    }
}

// ================= Kernel B: final deterministic combine (R8-proven shape) =================
__global__ __launch_bounds__(256)
void k_final(const float* __restrict__ ws_f, const float* __restrict__ partials,
             const int* __restrict__ seen, float* __restrict__ out) {
    const float4* p4 = (const float4*)partials;
    int t = threadIdx.x;
    float a0 = 0.f, a1 = 0.f, a2 = 0.f, a3 = 0.f;
    for (int j = t; j < NPART; j += 256) {
        float4 v = p4[j];
        a0 += v.x; a1 += v.y; a2 += v.z; a3 += v.w;
    }
    #pragma unroll
    for (int off = 32; off > 0; off >>= 1) {
        a0 += __shfl_down(a0, off);
        a1 += __shfl_down(a1, off);
        a2 += __shfl_down(a2, off);
        a3 += __shfl_down(a3, off);
    }
    __shared__ float s_w[4][4];
    int wave = t >> 6, lane = t & 63;
    if (lane == 0) {
        s_w[wave][0] = a0; s_w[wave][1] = a1; s_w[wave][2] = a2; s_w[wave][3] = a3;
    }
    __syncthreads();
    if (t == 0) {
        float r0 = s_w[0][0] + s_w[1][0] + s_w[2][0] + s_w[3][0];
        float r1 = s_w[0][1] + s_w[1][1] + s_w[2][1] + s_w[3][1];
        float r2 = s_w[0][2] + s_w[1][2] + s_w[2][2] + s_w[3][2];
        float r3 = s_w[0][3] + s_w[1][3] + s_w[2][3] + s_w[3][3];
        float loss_cls = ws_f[SUMS_OFF + 0] / (float)(NT * NC) * CLASS_SCALE;
        float loss_obj = ws_f[SUMS_OFF + 1] / (float)NT * OBJECT_SCALE;
        float loss_crd = ws_f[SUMS_OFF + 2] / (float)(NT * 4) * COORD_SCALE;
        float loss_no  = r0 / r1 * NOOBJ_SCALE;
        float total = loss_cls + loss_obj + loss_crd + loss_no;
        if (seen[0] < 12800) {
            total += r2 / (r3 * 4.f) * 0.01f;
        }
        out[0] = total;
    }
}

extern "C" void kernel_launch(void* const* d_in, const int* in_sizes, int n_in,
                              void* d_out, int out_size, void* d_ws, size_t ws_size,
                              hipStream_t stream) {
    const float* x    = (const float*)d_in[0];
    const float* tg   = (const float*)d_in[1];
    const int*   seen = (const int*)d_in[2];
    float* out  = (float*)d_out;
    float* ws_f = (float*)d_ws;
    float* partials = ws_f + PART_OFF;

    k_main<<<NBLK, NTHR, 0, stream>>>(x, tg, ws_f, partials);
    k_final<<<1, 256, 0, stream>>>(ws_f, partials, seen, out);
}